// Round 10
// baseline (359.210 us; speedup 1.0000x reference)
//
#include <hip/hip_runtime.h>
#include <hip/hip_bf16.h>
#include <cstdint>
#include <cstddef>

#define FIN 500
#define FH  128
#define FOUT 40
#define NB 256      // buckets (dst >> 9), 512 nodes each

typedef __attribute__((ext_vector_type(8))) short short8;
typedef __attribute__((ext_vector_type(4))) float f32x4;

__device__ inline float bf_lo(unsigned v) { unsigned t = v << 16; return __builtin_bit_cast(float, t); }
__device__ inline float bf_hi(unsigned v) { unsigned t = v & 0xffff0000u; return __builtin_bit_cast(float, t); }
__device__ inline unsigned short f2bf_bits(float f) {
  __hip_bfloat16 b = __float2bfloat16(f);
  return __builtin_bit_cast(unsigned short, b);
}

// ================= bucketed CSR build (ebin packed: (src<<9)|(dst&511)) =================

__global__ void __launch_bounds__(256) k_bcount(const int* __restrict__ dst,
                                                int* __restrict__ bucketCnt, int E) {
  __shared__ int lc[NB];
  int t = threadIdx.x;
  lc[t] = 0;
  __syncthreads();
  int base = blockIdx.x * 2048 + t * 8;
#pragma unroll
  for (int j = 0; j < 8; ++j) {
    int e = base + j;
    if (e < E) atomicAdd(&lc[dst[e] >> 9], 1);
  }
  __syncthreads();
  if (lc[t]) atomicAdd(&bucketCnt[t], lc[t]);
}

__global__ void k_bscan(const int* __restrict__ bucketCnt, int* __restrict__ bucketBase) {
  __shared__ int s[NB];
  int t = threadIdx.x;
  int v = bucketCnt[t];
  s[t] = v;
  __syncthreads();
  for (int o = 1; o < NB; o <<= 1) {
    int u = 0;
    if (t >= o) u = s[t - o];
    __syncthreads();
    if (t >= o) s[t] += u;
    __syncthreads();
  }
  bucketBase[t] = s[t] - v;
  if (t == NB - 1) bucketBase[NB] = s[NB - 1];
}

__global__ void __launch_bounds__(256) k_bin(const int* __restrict__ src,
                                             const int* __restrict__ dst,
                                             const int* __restrict__ bucketBase,
                                             int* __restrict__ bucketFill,
                                             unsigned* __restrict__ ebin, int E) {
  __shared__ int lc[NB];
  __shared__ int lbb[NB];
  int t = threadIdx.x;
  lc[t] = 0;
  lbb[t] = bucketBase[t];
  __syncthreads();
  int base = blockIdx.x * 2048 + t * 8;
  int rk[8], bk[8]; unsigned pk[8];
#pragma unroll
  for (int j = 0; j < 8; ++j) {
    int e = base + j;
    if (e < E) {
      int d = dst[e], s = src[e];
      bk[j] = d >> 9;
      pk[j] = ((unsigned)s << 9) | (unsigned)(d & 511);
      rk[j] = atomicAdd(&lc[bk[j]], 1);
    }
  }
  __syncthreads();
  int c = lc[t];
  int gb = 0;
  if (c) gb = atomicAdd(&bucketFill[t], c);
  __syncthreads();
  lc[t] = gb;
  __syncthreads();
#pragma unroll
  for (int j = 0; j < 8; ++j) {
    int e = base + j;
    if (e < E) {
      int pos = lbb[bk[j]] + lc[bk[j]] + rk[j];
      ebin[pos] = pk[j];
    }
  }
}

// per-bucket exact histogram; also emits dis = rsqrt(cnt+1) (k_dis fused in)
__global__ void __launch_bounds__(512) k_bhist(const unsigned* __restrict__ ebin,
                                               const int* __restrict__ bucketBase,
                                               int* __restrict__ cnt,
                                               float* __restrict__ dis, int N) {
  __shared__ int hc[512];
  int t = threadIdx.x, b = blockIdx.x;
  hc[t] = 0;
  __syncthreads();
  int s = bucketBase[b], e = bucketBase[b + 1];
  for (int i = s + t; i < e; i += 512) atomicAdd(&hc[ebin[i] & 511], 1);
  __syncthreads();
  int idx = b * 512 + t;
  if (idx < N) {
    int c = hc[t];
    cnt[idx] = c;
    dis[idx] = rsqrtf((float)c + 1.0f);
  }
}

__global__ void __launch_bounds__(512) k_fscatter(const unsigned* __restrict__ ebin,
                                                  const int* __restrict__ bucketBase,
                                                  const int* __restrict__ rp,
                                                  const float* __restrict__ dis,
                                                  int2* __restrict__ epackS, int N) {
  __shared__ int lrp[512];
  __shared__ float ldis[512];
  __shared__ int fill[512];
  int t = threadIdx.x, b = blockIdx.x;
  int n0 = b * 512 + t;
  lrp[t] = (n0 < N) ? rp[n0] : 0;
  ldis[t] = (n0 < N) ? dis[n0] : 0.f;
  fill[t] = 0;
  __syncthreads();
  int s = bucketBase[b], e = bucketBase[b + 1];
  for (int i = s + t; i < e; i += 512) {
    unsigned u = ebin[i];
    int ld = u & 511;
    int sn = u >> 9;
    int r = atomicAdd(&fill[ld], 1);
    float nm = dis[sn] * ldis[ld];
    epackS[lrp[ld] + r] = make_int2(sn << 7, __builtin_bit_cast(int, nm));
  }
}

// ---------------- scans ----------------

__global__ void k_scan1(const int* __restrict__ cnt, int* __restrict__ rp,
                        int* __restrict__ bsums, int n) {
  __shared__ int sums[256];
  int t = threadIdx.x;
  int base = blockIdx.x * 1024;
  int c[4]; int tot = 0;
#pragma unroll
  for (int j = 0; j < 4; ++j) {
    int idx = base + t * 4 + j;
    c[j] = (idx < n) ? cnt[idx] : 0;
    tot += c[j];
  }
  sums[t] = tot;
  __syncthreads();
  for (int off = 1; off < 256; off <<= 1) {
    int v = 0;
    if (t >= off) v = sums[t - off];
    __syncthreads();
    if (t >= off) sums[t] += v;
    __syncthreads();
  }
  int run = sums[t] - tot;
#pragma unroll
  for (int j = 0; j < 4; ++j) {
    int idx = base + t * 4 + j;
    if (idx < n) rp[idx] = run;
    run += c[j];
  }
  if (t == 255) bsums[blockIdx.x] = sums[255];
}

__global__ void k_scan2(int* __restrict__ bsums, int nb) {
  __shared__ int s[256];
  int t = threadIdx.x;
  int v = (t < nb) ? bsums[t] : 0;
  s[t] = v;
  __syncthreads();
  for (int off = 1; off < 256; off <<= 1) {
    int u = 0;
    if (t >= off) u = s[t - off];
    __syncthreads();
    if (t >= off) s[t] += u;
    __syncthreads();
  }
  if (t < nb) bsums[t] = s[t] - v;  // exclusive
}

__global__ void k_scan3(int* __restrict__ rp, const int* __restrict__ bsums, int n, int E) {
  int idx = blockIdx.x * 256 + threadIdx.x;
  if (idx < n) rp[idx] += bsums[idx >> 10];
  if (idx == n) rp[n] = E;
}

// ---------------- weight prep ----------------

__global__ void k_prep_w(const float* __restrict__ W, short* __restrict__ WT, int K, int KPAD) {
  int idx = blockIdx.x * 256 + threadIdx.x;
  if (idx >= 128 * KPAD) return;
  int c = idx / KPAD, k = idx - c * KPAD;
  WT[idx] = (k < K) ? (short)f2bf_bits(W[(size_t)k * FH + c]) : (short)0;
}

__global__ void k_prep_wfc(const float* __restrict__ Wfc, short* __restrict__ WfcT) {
  int idx = blockIdx.x * 256 + threadIdx.x;
  if (idx >= 48 * 128) return;
  int c = idx >> 7, k = idx & 127;
  WfcT[idx] = (c < FOUT) ? (short)f2bf_bits(Wfc[(size_t)k * FOUT + c]) : (short)0;
}

// ---------------- streaming MFMA GEMM: B staged in LDS ONCE, barrier-free ----------------
// (r8/r9 structure, proven.)

template<int KP, bool AF32>
__global__ void __launch_bounds__(512) k_gemm_q(const void* __restrict__ Aptr,
                                                const short* __restrict__ WT,
                                                unsigned char* __restrict__ hQ,
                                                float* __restrict__ scale,
                                                int M, int K) {
  constexpr int KPB = KP * 2;        // LDS row bytes
  constexpr int NKT = KP / 32;       // K-steps
  __shared__ char sB[128 * KPB];
  __shared__ unsigned char lq[8][16 * 128];
  const int tid = threadIdx.x;
  const int wave = tid >> 6, lane = tid & 63;
  const int lr = lane & 15, g = lane >> 4;
  const int swz = (lr & 7) << 4;     // per-lane XOR swizzle (T2)

  // ---- stage all of B into LDS (swizzled), once ----
  for (int idx = tid; idx < 16 * KP; idx += 512) {   // 16B chunks
    int c = idx / (KP / 8);
    int kq = idx - c * (KP / 8);
    short8 v = *(const short8*)(WT + (size_t)c * KP + kq * 8);
    *(short8*)(sB + (size_t)c * KPB + ((kq * 16) ^ ((c & 7) << 4))) = v;
  }
  __syncthreads();   // the ONLY block-wide barrier

  const int nStrips = M >> 4;        // M % 16 == 0
  for (int sid = blockIdx.x * 8 + wave; sid < nStrips; sid += gridDim.x * 8) {
    const int rowbase = sid * 16;
    const int arow = rowbase + lr;

    f32x4 acc[8];
#pragma unroll
    for (int j = 0; j < 8; ++j) acc[j] = (f32x4){0.f, 0.f, 0.f, 0.f};

    auto loadA = [&](int kt, short8& dstv) {
      const int k0 = kt * 32 + g * 8;
      if constexpr (AF32) {
        const float* A = (const float*)Aptr + (size_t)arow * K;
        float f[8];
        if (k0 + 8 <= K) {
          float4 u0 = *(const float4*)(A + k0);
          float4 u1 = *(const float4*)(A + k0 + 4);
          f[0] = u0.x; f[1] = u0.y; f[2] = u0.z; f[3] = u0.w;
          f[4] = u1.x; f[5] = u1.y; f[6] = u1.z; f[7] = u1.w;
        } else {
#pragma unroll
          for (int j = 0; j < 8; ++j) f[j] = (k0 + j < K) ? A[k0 + j] : 0.f;
        }
#pragma unroll
        for (int j = 0; j < 8; ++j) dstv[j] = (short)f2bf_bits(f[j]);
      } else {
        dstv = *(const short8*)((const short*)Aptr + (size_t)arow * K + k0);
      }
    };

    // 2-deep software pipeline on the A stream (named regs, rule #20)
    short8 aCur, aNx1, aNx2;
    loadA(0, aCur);
    if (NKT > 1) loadA(1, aNx1);
#pragma unroll
    for (int kt = 0; kt < NKT; ++kt) {
      if (kt + 2 < NKT) loadA(kt + 2, aNx2);
      const int kofs = (kt * 64 + g * 16) ^ swz;
#pragma unroll
      for (int j = 0; j < 8; ++j) {
        short8 b = *(const short8*)(sB + (size_t)(j * 16 + lr) * KPB + kofs);
        acc[j] = __builtin_amdgcn_mfma_f32_16x16x32_bf16(aCur, b, acc[j], 0, 0, 0);
      }
      aCur = aNx1; aNx1 = aNx2;
    }

    // ---- fused per-row int8 quantization ----
    float mx[4];
#pragma unroll
    for (int r = 0; r < 4; ++r) {
      float m = 0.f;
#pragma unroll
      for (int j = 0; j < 8; ++j) m = fmaxf(m, fabsf(acc[j][r]));
#pragma unroll
      for (int s = 1; s < 16; s <<= 1) m = fmaxf(m, __shfl_xor(m, s));
      mx[r] = m;
    }
    if (lr == 0) {
      float4 sv = make_float4(mx[0] * (1.f / 127.f), mx[1] * (1.f / 127.f),
                              mx[2] * (1.f / 127.f), mx[3] * (1.f / 127.f));
      *(float4*)(scale + rowbase + g * 4) = sv;
    }
    float rs[4];
#pragma unroll
    for (int r = 0; r < 4; ++r) rs[r] = (mx[r] > 0.f) ? 127.f / mx[r] : 0.f;
#pragma unroll
    for (int j = 0; j < 8; ++j) {
#pragma unroll
      for (int r = 0; r < 4; ++r) {
        int q = (int)rintf(acc[j][r] * rs[r]);
        lq[wave][(g * 4 + r) * 128 + j * 16 + lr] = (unsigned char)(signed char)q;
      }
    }
    asm volatile("s_waitcnt lgkmcnt(0)" ::: "memory");
    __builtin_amdgcn_sched_barrier(0);
    {
      int o = lane * 32;
      *(uint4*)(hQ + (size_t)rowbase * 128 + o) = *(const uint4*)(&lq[wave][o]);
      *(uint4*)(hQ + (size_t)rowbase * 128 + o + 16) = *(const uint4*)(&lq[wave][o + 16]);
    }
  }
}

// ---------------- aggregation v6: 3-stage pipeline ----------------
// Stage A (i+2): pack+scale prefetch.  Stage B (i+1): bpermute distribution.
// Stage C (i): gathers issue at loop top, FMAs at bottom — iteration i+1's
// bpermutes execute while i's gathers are in flight, so the LDS-latency
// bpermute chain no longer serializes with the L2/L3 gather latency.

__global__ void __launch_bounds__(256) k_agg(const char* __restrict__ hQbytes,
                                             const float* __restrict__ scale,
                                             char* __restrict__ outbytes,
                                             const float* __restrict__ dis,
                                             const int* __restrict__ rp,
                                             const int2* __restrict__ epackS,
                                             const float* __restrict__ bias,
                                             int N) {
  int node = blockIdx.x * 4 + (threadIdx.x >> 6);
  int lane = threadIdx.x & 63;
  if (node >= N) return;
  const int q = lane & 31;
  const int hi = lane >> 5;
  const int e0 = rp[node], end = rp[node + 1];
  const int vbp = hi * 4;

  auto loadPack = [&](int e, int2& p, float& ps) {
    p = make_int2(0, 0); ps = 0.f;
    if (lane < 16 && e + lane < end) {
      p = epackS[e + lane];
      ps = scale[(unsigned)p.x >> 7];
    }
  };
  auto bperm = [&](const int2& p, float ps, int* offs, float* wts) {
    float w = __builtin_bit_cast(float, p.y) * ps;
    int wb = __builtin_bit_cast(int, w);
#pragma unroll
    for (int j = 0; j < 8; ++j) {
      int idx4 = vbp + 8 * j;
      offs[j] = __builtin_amdgcn_ds_bpermute(idx4, p.x);
      wts[j] = __builtin_bit_cast(float, __builtin_amdgcn_ds_bpermute(idx4, wb));
    }
  };

  float a0 = 0.f, a1 = 0.f, a2 = 0.f, a3 = 0.f;
  if (hi == 0) {   // self term: deq from hQ (w = scale[node]/deg)
    float w = dis[node]; w = w * w * scale[node];
    int sv = *(const int*)(hQbytes + (size_t)node * 128 + q * 4);
    a0 = w * (float)((sv << 24) >> 24);
    a1 = w * (float)((sv << 16) >> 24);
    a2 = w * (float)((sv << 8) >> 24);
    a3 = w * (float)(sv >> 24);
  }

  // pipeline priming: packs for iter 0,1; bpermute for iter 0
  int2 pA; float sA2;
  int2 pB; float sB2;
  loadPack(e0, pA, sA2);
  loadPack(e0 + 16, pB, sB2);
  int off[8]; float wts[8];
  bperm(pA, sA2, off, wts);

  for (int e = e0; e < end; e += 16) {
    // stage C: issue current gathers
    int vv[8];
#pragma unroll
    for (int j = 0; j < 8; ++j)
      vv[j] = *(const int*)(hQbytes + (size_t)(unsigned)(off[j] + q * 4));
    // stage A: prefetch packs for i+2
    int2 pC; float sC2;
    loadPack(e + 32, pC, sC2);
    // stage B: bpermute for i+1 (overlaps current gather latency)
    int offN[8]; float wtsN[8];
    bperm(pB, sB2, offN, wtsN);
    // stage C': consume current gathers
#pragma unroll
    for (int j = 0; j < 8; ++j) {
      int d = vv[j];
      float n = wts[j];
      a0 += n * (float)((d << 24) >> 24);
      a1 += n * (float)((d << 16) >> 24);
      a2 += n * (float)((d << 8) >> 24);
      a3 += n * (float)(d >> 24);
    }
    // rotate pipeline state (static indexing)
#pragma unroll
    for (int j = 0; j < 8; ++j) { off[j] = offN[j]; wts[j] = wtsN[j]; }
    pB = pC; sB2 = sC2;
  }
  a0 += __shfl_xor(a0, 32); a1 += __shfl_xor(a1, 32);
  a2 += __shfl_xor(a2, 32); a3 += __shfl_xor(a3, 32);
  if (hi == 0) {
    float4 bv = *(const float4*)(bias + 4 * q);
    a0 = fmaxf(a0 + bv.x, 0.f); a1 = fmaxf(a1 + bv.y, 0.f);
    a2 = fmaxf(a2 + bv.z, 0.f); a3 = fmaxf(a3 + bv.w, 0.f);
    uint2 r;
    r.x = ((unsigned)f2bf_bits(a1) << 16) | (unsigned)f2bf_bits(a0);
    r.y = ((unsigned)f2bf_bits(a3) << 16) | (unsigned)f2bf_bits(a2);
    *(uint2*)(outbytes + (size_t)node * 256 + q * 8) = r;
  }
}

// ---------------- fused logits + log_softmax via MFMA ----------------

__global__ void __launch_bounds__(256) k_logits(const short* __restrict__ h,
                                                const short* __restrict__ WfcT,
                                                const float* __restrict__ bfc,
                                                float* __restrict__ out, int N) {
  const int wave = threadIdx.x >> 6, lane = threadIdx.x & 63;
  const int lr = lane & 15, g = lane >> 4;
  const int nbase = blockIdx.x * 64 + wave * 16;
  int arow = nbase + lr; if (arow >= N) arow = N - 1;
  const short* ap = h + (size_t)arow * FH;
  short8 af[4];
#pragma unroll
  for (int ks = 0; ks < 4; ++ks)
    af[ks] = *(const short8*)(ap + ks * 32 + g * 8);
  f32x4 acc[3];
#pragma unroll
  for (int t = 0; t < 3; ++t) {
    acc[t] = (f32x4){0.f, 0.f, 0.f, 0.f};
    const short* bp = WfcT + (size_t)(t * 16 + lr) * FH;
#pragma unroll
    for (int ks = 0; ks < 4; ++ks) {
      short8 bf = *(const short8*)(bp + ks * 32 + g * 8);
      acc[t] = __builtin_amdgcn_mfma_f32_16x16x32_bf16(af[ks], bf, acc[t], 0, 0, 0);
    }
  }
  float bb[3];
#pragma unroll
  for (int t = 0; t < 3; ++t) { int c = t * 16 + lr; bb[t] = (c < FOUT) ? bfc[c] : 0.f; }
  const bool v2 = (lr < 8);
  float res[3][4];
#pragma unroll
  for (int r = 0; r < 4; ++r) {
    float l0 = acc[0][r] + bb[0];
    float l1 = acc[1][r] + bb[1];
    float l2 = v2 ? (acc[2][r] + bb[2]) : -INFINITY;
    float mm = fmaxf(fmaxf(l0, l1), l2);
#pragma unroll
    for (int s = 1; s < 16; s <<= 1) mm = fmaxf(mm, __shfl_xor(mm, s));
    float e0 = expf(l0 - mm), e1 = expf(l1 - mm), e2 = v2 ? expf(l2 - mm) : 0.f;
    float ss = e0 + e1 + e2;
#pragma unroll
    for (int s = 1; s < 16; s <<= 1) ss += __shfl_xor(ss, s);
    float lse = mm + logf(ss);
    res[0][r] = l0 - lse; res[1][r] = l1 - lse; res[2][r] = l2 - lse;
  }
#pragma unroll
  for (int t = 0; t < 3; ++t) {
    int c = t * 16 + lr;
    if (c < FOUT) {
#pragma unroll
      for (int r = 0; r < 4; ++r) {
        int node = nbase + g * 4 + r;
        if (node < N) out[(size_t)node * FOUT + c] = res[t][r];
      }
    }
  }
}

// ---------------- host ----------------

static inline size_t align_up(size_t x, size_t a) { return (x + a - 1) & ~(a - 1); }

extern "C" void kernel_launch(void* const* d_in, const int* in_sizes, int n_in,
                              void* d_out, int out_size, void* d_ws, size_t ws_size,
                              hipStream_t stream) {
  const float* x   = (const float*)d_in[0];
  const int*   ei  = (const int*)d_in[1];
  const float* W0  = (const float*)d_in[2];
  const float* b0  = (const float*)d_in[3];
  const float* W1  = (const float*)d_in[4];
  const float* b1  = (const float*)d_in[5];
  const float* W2  = (const float*)d_in[6];
  const float* b2  = (const float*)d_in[7];
  const float* Wfc = (const float*)d_in[8];
  const float* bfc = (const float*)d_in[9];
  float* out = (float*)d_out;

  const int N = in_sizes[0] / FIN;       // 100000
  const int E = in_sizes[1] / 2;         // 1600000
  const int* src = ei;
  const int* dst = ei + E;
  const int KP0 = 512;

  // workspace layout
  char* ws = (char*)d_ws;
  size_t off = 0;
  int* cnt = (int*)(ws + off);            off = align_up(off + (size_t)N * 4, 512);
  float* dis = (float*)(ws + off);        off = align_up(off + (size_t)N * 4, 512);
  int* rp = (int*)(ws + off);             off = align_up(off + (size_t)(N + 1) * 4, 512);
  int* bsums = (int*)(ws + off);          off = align_up(off + 4096, 512);
  int* bucketCnt = (int*)(ws + off);      off = align_up(off + (NB + 1) * 4, 512);
  int* bucketBase = (int*)(ws + off);     off = align_up(off + (NB + 1) * 4, 512);
  int* bucketFill = (int*)(ws + off);     off = align_up(off + (NB + 1) * 4, 512);
  unsigned* ebin = (unsigned*)(ws + off); off = align_up(off + (size_t)E * 4, 512);
  int2* epackS = (int2*)(ws + off);       off = align_up(off + (size_t)E * 8, 512);
  short* WT0 = (short*)(ws + off);        off = align_up(off + (size_t)128 * KP0 * 2, 512);
  short* WT1 = (short*)(ws + off);        off = align_up(off + (size_t)128 * FH * 2, 512);
  short* WT2 = (short*)(ws + off);        off = align_up(off + (size_t)128 * FH * 2, 512);
  short* WfcT = (short*)(ws + off);       off = align_up(off + (size_t)48 * FH * 2, 512);
  short* hB = (short*)(ws + off);         off = align_up(off + (size_t)N * FH * 2, 512);
  float* scale = (float*)(ws + off);      off = align_up(off + (size_t)N * 4, 512);
  unsigned char* hQ = (unsigned char*)(ws + off); off = align_up(off + (size_t)N * 128, 512);

  const int nbScan = (N + 1023) / 1024;
  const int gN4 = (N + 3) / 4;
  const int gBlk = (E + 2047) / 2048;
  const int NBUSE = (N + 511) / 512;

  // --- bucketed CSR build ---
  hipMemsetAsync(bucketCnt, 0, (NB + 1) * 4, stream);
  hipMemsetAsync(bucketFill, 0, (NB + 1) * 4, stream);
  k_bcount<<<gBlk, 256, 0, stream>>>(dst, bucketCnt, E);
  k_bscan<<<1, NB, 0, stream>>>(bucketCnt, bucketBase);
  k_bin<<<gBlk, 256, 0, stream>>>(src, dst, bucketBase, bucketFill, ebin, E);
  k_bhist<<<NBUSE, 512, 0, stream>>>(ebin, bucketBase, cnt, dis, N);
  k_scan1<<<nbScan, 256, 0, stream>>>(cnt, rp, bsums, N);
  k_scan2<<<1, 256, 0, stream>>>(bsums, nbScan);
  k_scan3<<<(N + 1 + 255) / 256, 256, 0, stream>>>(rp, bsums, N, E);
  k_fscatter<<<NBUSE, 512, 0, stream>>>(ebin, bucketBase, rp, dis, epackS, N);

  // --- weight prep ---
  k_prep_w<<<(128 * KP0 + 255) / 256, 256, 0, stream>>>(W0, WT0, FIN, KP0);
  k_prep_w<<<(128 * FH + 255) / 256, 256, 0, stream>>>(W1, WT1, FH, FH);
  k_prep_w<<<(128 * FH + 255) / 256, 256, 0, stream>>>(W2, WT2, FH, FH);
  k_prep_wfc<<<(48 * FH + 255) / 256, 256, 0, stream>>>(Wfc, WfcT);

  const int gLog = (N + 63) / 64;

  // --- layer 0: 500 -> 128 ---
  k_gemm_q<512, true><<<256, 512, 0, stream>>>(x, WT0, hQ, scale, N, FIN);
  k_agg<<<gN4, 256, 0, stream>>>((const char*)hQ, scale, (char*)hB, dis, rp, epackS, b0, N);
  // --- layer 1 ---
  k_gemm_q<128, false><<<256, 512, 0, stream>>>(hB, WT1, hQ, scale, N, FH);
  k_agg<<<gN4, 256, 0, stream>>>((const char*)hQ, scale, (char*)hB, dis, rp, epackS, b1, N);
  // --- layer 2 ---
  k_gemm_q<128, false><<<256, 512, 0, stream>>>(hB, WT2, hQ, scale, N, FH);
  k_agg<<<gN4, 256, 0, stream>>>((const char*)hQ, scale, (char*)hB, dis, rp, epackS, b2, N);
  // --- FC + log_softmax ---
  k_logits<<<gLog, 256, 0, stream>>>(hB, WfcT, bfc, out, N);
}

// Round 11
// 336.805 us; speedup vs baseline: 1.0665x; 1.0665x over previous
//
#include <hip/hip_runtime.h>
#include <hip/hip_bf16.h>
#include <cstdint>
#include <cstddef>

#define FIN 500
#define FH  128
#define FOUT 40
#define NB 256      // buckets (dst >> 9), 512 nodes each

typedef __attribute__((ext_vector_type(8))) short short8;
typedef __attribute__((ext_vector_type(4))) float f32x4;

__device__ inline float bf_lo(unsigned v) { unsigned t = v << 16; return __builtin_bit_cast(float, t); }
__device__ inline float bf_hi(unsigned v) { unsigned t = v & 0xffff0000u; return __builtin_bit_cast(float, t); }
__device__ inline unsigned short f2bf_bits(float f) {
  __hip_bfloat16 b = __float2bfloat16(f);
  return __builtin_bit_cast(unsigned short, b);
}

// ================= bucketed CSR build (ebin packed: (src<<9)|(dst&511)) =================

__global__ void __launch_bounds__(256) k_bcount(const int* __restrict__ dst,
                                                int* __restrict__ bucketCnt, int E) {
  __shared__ int lc[NB];
  int t = threadIdx.x;
  lc[t] = 0;
  __syncthreads();
  int base = blockIdx.x * 2048 + t * 8;
#pragma unroll
  for (int j = 0; j < 8; ++j) {
    int e = base + j;
    if (e < E) atomicAdd(&lc[dst[e] >> 9], 1);
  }
  __syncthreads();
  if (lc[t]) atomicAdd(&bucketCnt[t], lc[t]);
}

__global__ void k_bscan(const int* __restrict__ bucketCnt, int* __restrict__ bucketBase) {
  __shared__ int s[NB];
  int t = threadIdx.x;
  int v = bucketCnt[t];
  s[t] = v;
  __syncthreads();
  for (int o = 1; o < NB; o <<= 1) {
    int u = 0;
    if (t >= o) u = s[t - o];
    __syncthreads();
    if (t >= o) s[t] += u;
    __syncthreads();
  }
  bucketBase[t] = s[t] - v;
  if (t == NB - 1) bucketBase[NB] = s[NB - 1];
}

__global__ void __launch_bounds__(256) k_bin(const int* __restrict__ src,
                                             const int* __restrict__ dst,
                                             const int* __restrict__ bucketBase,
                                             int* __restrict__ bucketFill,
                                             unsigned* __restrict__ ebin, int E) {
  __shared__ int lc[NB];
  __shared__ int lbb[NB];
  int t = threadIdx.x;
  lc[t] = 0;
  lbb[t] = bucketBase[t];
  __syncthreads();
  int base = blockIdx.x * 2048 + t * 8;
  int rk[8], bk[8]; unsigned pk[8];
#pragma unroll
  for (int j = 0; j < 8; ++j) {
    int e = base + j;
    if (e < E) {
      int d = dst[e], s = src[e];
      bk[j] = d >> 9;
      pk[j] = ((unsigned)s << 9) | (unsigned)(d & 511);
      rk[j] = atomicAdd(&lc[bk[j]], 1);
    }
  }
  __syncthreads();
  int c = lc[t];
  int gb = 0;
  if (c) gb = atomicAdd(&bucketFill[t], c);
  __syncthreads();
  lc[t] = gb;
  __syncthreads();
#pragma unroll
  for (int j = 0; j < 8; ++j) {
    int e = base + j;
    if (e < E) {
      int pos = lbb[bk[j]] + lc[bk[j]] + rk[j];
      ebin[pos] = pk[j];
    }
  }
}

// per-bucket exact histogram -> dis AND rp directly:
// bucketBase[b] IS the global degree prefix at node b*512, so
// rp[node] = bucketBase[b] + exclusive-scan(hist) within the bucket.
// (k_dis + k_scan1/2/3 all fused away.)
__global__ void __launch_bounds__(512) k_bhist(const unsigned* __restrict__ ebin,
                                               const int* __restrict__ bucketBase,
                                               int* __restrict__ rp,
                                               float* __restrict__ dis, int N, int E) {
  __shared__ int hc[512];
  __shared__ int sc[512];
  int t = threadIdx.x, b = blockIdx.x;
  hc[t] = 0;
  __syncthreads();
  int s = bucketBase[b], e = bucketBase[b + 1];
  for (int i = s + t; i < e; i += 512) atomicAdd(&hc[ebin[i] & 511], 1);
  __syncthreads();
  int c = hc[t];
  sc[t] = c;
  __syncthreads();
  for (int o = 1; o < 512; o <<= 1) {
    int u = 0;
    if (t >= o) u = sc[t - o];
    __syncthreads();
    if (t >= o) sc[t] += u;
    __syncthreads();
  }
  int idx = b * 512 + t;
  if (idx < N) {
    rp[idx] = s + sc[t] - c;               // exclusive prefix
    dis[idx] = rsqrtf((float)c + 1.0f);    // deg includes self-loop
  }
  if (b == 0 && t == 0) rp[N] = E;
}

__global__ void __launch_bounds__(512) k_fscatter(const unsigned* __restrict__ ebin,
                                                  const int* __restrict__ bucketBase,
                                                  const int* __restrict__ rp,
                                                  const float* __restrict__ dis,
                                                  int2* __restrict__ epackS, int N) {
  __shared__ int lrp[512];
  __shared__ float ldis[512];
  __shared__ int fill[512];
  int t = threadIdx.x, b = blockIdx.x;
  int n0 = b * 512 + t;
  lrp[t] = (n0 < N) ? rp[n0] : 0;
  ldis[t] = (n0 < N) ? dis[n0] : 0.f;
  fill[t] = 0;
  __syncthreads();
  int s = bucketBase[b], e = bucketBase[b + 1];
  for (int i = s + t; i < e; i += 512) {
    unsigned u = ebin[i];
    int ld = u & 511;
    int sn = u >> 9;
    int r = atomicAdd(&fill[ld], 1);
    float nm = dis[sn] * ldis[ld];
    epackS[lrp[ld] + r] = make_int2(sn << 7, __builtin_bit_cast(int, nm));
  }
}

// ---------------- weight prep ----------------

__global__ void k_prep_w(const float* __restrict__ W, short* __restrict__ WT, int K, int KPAD) {
  int idx = blockIdx.x * 256 + threadIdx.x;
  if (idx >= 128 * KPAD) return;
  int c = idx / KPAD, k = idx - c * KPAD;
  WT[idx] = (k < K) ? (short)f2bf_bits(W[(size_t)k * FH + c]) : (short)0;
}

__global__ void k_prep_wfc(const float* __restrict__ Wfc, short* __restrict__ WfcT) {
  int idx = blockIdx.x * 256 + threadIdx.x;
  if (idx >= 48 * 128) return;
  int c = idx >> 7, k = idx & 127;
  WfcT[idx] = (c < FOUT) ? (short)f2bf_bits(Wfc[(size_t)k * FOUT + c]) : (short)0;
}

// ---------------- streaming MFMA GEMM: B staged in LDS ONCE, barrier-free ----------------
// (r8/r9 structure, proven.)

template<int KP, bool AF32>
__global__ void __launch_bounds__(512) k_gemm_q(const void* __restrict__ Aptr,
                                                const short* __restrict__ WT,
                                                unsigned char* __restrict__ hQ,
                                                float* __restrict__ scale,
                                                int M, int K) {
  constexpr int KPB = KP * 2;        // LDS row bytes
  constexpr int NKT = KP / 32;       // K-steps
  __shared__ char sB[128 * KPB];
  __shared__ unsigned char lq[8][16 * 128];
  const int tid = threadIdx.x;
  const int wave = tid >> 6, lane = tid & 63;
  const int lr = lane & 15, g = lane >> 4;
  const int swz = (lr & 7) << 4;     // per-lane XOR swizzle (T2)

  // ---- stage all of B into LDS (swizzled), once ----
  for (int idx = tid; idx < 16 * KP; idx += 512) {   // 16B chunks
    int c = idx / (KP / 8);
    int kq = idx - c * (KP / 8);
    short8 v = *(const short8*)(WT + (size_t)c * KP + kq * 8);
    *(short8*)(sB + (size_t)c * KPB + ((kq * 16) ^ ((c & 7) << 4))) = v;
  }
  __syncthreads();   // the ONLY block-wide barrier

  const int nStrips = M >> 4;        // M % 16 == 0
  for (int sid = blockIdx.x * 8 + wave; sid < nStrips; sid += gridDim.x * 8) {
    const int rowbase = sid * 16;
    const int arow = rowbase + lr;

    f32x4 acc[8];
#pragma unroll
    for (int j = 0; j < 8; ++j) acc[j] = (f32x4){0.f, 0.f, 0.f, 0.f};

    auto loadA = [&](int kt, short8& dstv) {
      const int k0 = kt * 32 + g * 8;
      if constexpr (AF32) {
        const float* A = (const float*)Aptr + (size_t)arow * K;
        float f[8];
        if (k0 + 8 <= K) {
          float4 u0 = *(const float4*)(A + k0);
          float4 u1 = *(const float4*)(A + k0 + 4);
          f[0] = u0.x; f[1] = u0.y; f[2] = u0.z; f[3] = u0.w;
          f[4] = u1.x; f[5] = u1.y; f[6] = u1.z; f[7] = u1.w;
        } else {
#pragma unroll
          for (int j = 0; j < 8; ++j) f[j] = (k0 + j < K) ? A[k0 + j] : 0.f;
        }
#pragma unroll
        for (int j = 0; j < 8; ++j) dstv[j] = (short)f2bf_bits(f[j]);
      } else {
        dstv = *(const short8*)((const short*)Aptr + (size_t)arow * K + k0);
      }
    };

    // 2-deep software pipeline on the A stream (named regs, rule #20)
    short8 aCur, aNx1, aNx2;
    loadA(0, aCur);
    if (NKT > 1) loadA(1, aNx1);
#pragma unroll
    for (int kt = 0; kt < NKT; ++kt) {
      if (kt + 2 < NKT) loadA(kt + 2, aNx2);
      const int kofs = (kt * 64 + g * 16) ^ swz;
#pragma unroll
      for (int j = 0; j < 8; ++j) {
        short8 b = *(const short8*)(sB + (size_t)(j * 16 + lr) * KPB + kofs);
        acc[j] = __builtin_amdgcn_mfma_f32_16x16x32_bf16(aCur, b, acc[j], 0, 0, 0);
      }
      aCur = aNx1; aNx1 = aNx2;
    }

    // ---- fused per-row int8 quantization ----
    float mx[4];
#pragma unroll
    for (int r = 0; r < 4; ++r) {
      float m = 0.f;
#pragma unroll
      for (int j = 0; j < 8; ++j) m = fmaxf(m, fabsf(acc[j][r]));
#pragma unroll
      for (int s = 1; s < 16; s <<= 1) m = fmaxf(m, __shfl_xor(m, s));
      mx[r] = m;
    }
    if (lr == 0) {
      float4 sv = make_float4(mx[0] * (1.f / 127.f), mx[1] * (1.f / 127.f),
                              mx[2] * (1.f / 127.f), mx[3] * (1.f / 127.f));
      *(float4*)(scale + rowbase + g * 4) = sv;
    }
    float rs[4];
#pragma unroll
    for (int r = 0; r < 4; ++r) rs[r] = (mx[r] > 0.f) ? 127.f / mx[r] : 0.f;
#pragma unroll
    for (int j = 0; j < 8; ++j) {
#pragma unroll
      for (int r = 0; r < 4; ++r) {
        int q = (int)rintf(acc[j][r] * rs[r]);
        lq[wave][(g * 4 + r) * 128 + j * 16 + lr] = (unsigned char)(signed char)q;
      }
    }
    asm volatile("s_waitcnt lgkmcnt(0)" ::: "memory");
    __builtin_amdgcn_sched_barrier(0);
    {
      int o = lane * 32;
      *(uint4*)(hQ + (size_t)rowbase * 128 + o) = *(const uint4*)(&lq[wave][o]);
      *(uint4*)(hQ + (size_t)rowbase * 128 + o + 16) = *(const uint4*)(&lq[wave][o + 16]);
    }
  }
}

// ---------------- aggregation (r9 version, proven fastest; r10 3-stage reverted) ----------------
// One wave per node. Lanes 0-31 even edges, 32-63 odd edges; each lane loads
// one dword = 4 int8 features. Packs+scales loaded by lanes 0-15 (prefetched
// one iteration ahead), distributed via ds_bpermute. Self term deq from hQ.

__global__ void __launch_bounds__(256) k_agg(const char* __restrict__ hQbytes,
                                             const float* __restrict__ scale,
                                             char* __restrict__ outbytes,
                                             const float* __restrict__ dis,
                                             const int* __restrict__ rp,
                                             const int2* __restrict__ epackS,
                                             const float* __restrict__ bias,
                                             int N) {
  int node = blockIdx.x * 4 + (threadIdx.x >> 6);
  int lane = threadIdx.x & 63;
  if (node >= N) return;
  const int q = lane & 31;
  const int hi = lane >> 5;
  const int e0 = rp[node], end = rp[node + 1];
  int2 p = make_int2(0, 0);
  float psc = 0.f;
  if (lane < 16 && e0 + lane < end) {
    p = epackS[e0 + lane];
    psc = scale[(unsigned)p.x >> 7];
  }
  float a0 = 0.f, a1 = 0.f, a2 = 0.f, a3 = 0.f;
  if (hi == 0) {   // self term: deq from hQ (w = scale[node]/deg)
    float w = dis[node]; w = w * w * scale[node];
    int sv = *(const int*)(hQbytes + (size_t)node * 128 + q * 4);
    a0 = w * (float)((sv << 24) >> 24);
    a1 = w * (float)((sv << 16) >> 24);
    a2 = w * (float)((sv << 8) >> 24);
    a3 = w * (float)(sv >> 24);
  }
  const int vbp = hi * 4;
  for (int e = e0; e < end; e += 16) {
    int2 pn = make_int2(0, 0);
    float pnsc = 0.f;
    if (lane < 16 && e + 16 + lane < end) {          // prefetch next packs+scales
      pn = epackS[e + 16 + lane];
      pnsc = scale[(unsigned)pn.x >> 7];
    }
    float wcur = __builtin_bit_cast(float, p.y) * psc;  // norm * scale[src]
    int wbits = __builtin_bit_cast(int, wcur);
    int vv[8]; float nn[8];
#pragma unroll
    for (int j = 0; j < 8; ++j) {
      int idx4 = vbp + 8 * j;
      int off = __builtin_amdgcn_ds_bpermute(idx4, p.x);
      int nb  = __builtin_amdgcn_ds_bpermute(idx4, wbits);
      nn[j] = __builtin_bit_cast(float, nb);
      vv[j] = *(const int*)(hQbytes + (size_t)(unsigned)(off + q * 4));
    }
#pragma unroll
    for (int j = 0; j < 8; ++j) {
      int d = vv[j];
      float n = nn[j];
      a0 += n * (float)((d << 24) >> 24);
      a1 += n * (float)((d << 16) >> 24);
      a2 += n * (float)((d << 8) >> 24);
      a3 += n * (float)(d >> 24);
    }
    p = pn; psc = pnsc;
  }
  a0 += __shfl_xor(a0, 32); a1 += __shfl_xor(a1, 32);
  a2 += __shfl_xor(a2, 32); a3 += __shfl_xor(a3, 32);
  if (hi == 0) {
    float4 bv = *(const float4*)(bias + 4 * q);
    a0 = fmaxf(a0 + bv.x, 0.f); a1 = fmaxf(a1 + bv.y, 0.f);
    a2 = fmaxf(a2 + bv.z, 0.f); a3 = fmaxf(a3 + bv.w, 0.f);
    uint2 r;
    r.x = ((unsigned)f2bf_bits(a1) << 16) | (unsigned)f2bf_bits(a0);
    r.y = ((unsigned)f2bf_bits(a3) << 16) | (unsigned)f2bf_bits(a2);
    *(uint2*)(outbytes + (size_t)node * 256 + q * 8) = r;
  }
}

// ---------------- fused logits + log_softmax via MFMA ----------------

__global__ void __launch_bounds__(256) k_logits(const short* __restrict__ h,
                                                const short* __restrict__ WfcT,
                                                const float* __restrict__ bfc,
                                                float* __restrict__ out, int N) {
  const int wave = threadIdx.x >> 6, lane = threadIdx.x & 63;
  const int lr = lane & 15, g = lane >> 4;
  const int nbase = blockIdx.x * 64 + wave * 16;
  int arow = nbase + lr; if (arow >= N) arow = N - 1;
  const short* ap = h + (size_t)arow * FH;
  short8 af[4];
#pragma unroll
  for (int ks = 0; ks < 4; ++ks)
    af[ks] = *(const short8*)(ap + ks * 32 + g * 8);
  f32x4 acc[3];
#pragma unroll
  for (int t = 0; t < 3; ++t) {
    acc[t] = (f32x4){0.f, 0.f, 0.f, 0.f};
    const short* bp = WfcT + (size_t)(t * 16 + lr) * FH;
#pragma unroll
    for (int ks = 0; ks < 4; ++ks) {
      short8 bf = *(const short8*)(bp + ks * 32 + g * 8);
      acc[t] = __builtin_amdgcn_mfma_f32_16x16x32_bf16(af[ks], bf, acc[t], 0, 0, 0);
    }
  }
  float bb[3];
#pragma unroll
  for (int t = 0; t < 3; ++t) { int c = t * 16 + lr; bb[t] = (c < FOUT) ? bfc[c] : 0.f; }
  const bool v2 = (lr < 8);
  float res[3][4];
#pragma unroll
  for (int r = 0; r < 4; ++r) {
    float l0 = acc[0][r] + bb[0];
    float l1 = acc[1][r] + bb[1];
    float l2 = v2 ? (acc[2][r] + bb[2]) : -INFINITY;
    float mm = fmaxf(fmaxf(l0, l1), l2);
#pragma unroll
    for (int s = 1; s < 16; s <<= 1) mm = fmaxf(mm, __shfl_xor(mm, s));
    float e0 = expf(l0 - mm), e1 = expf(l1 - mm), e2 = v2 ? expf(l2 - mm) : 0.f;
    float ss = e0 + e1 + e2;
#pragma unroll
    for (int s = 1; s < 16; s <<= 1) ss += __shfl_xor(ss, s);
    float lse = mm + logf(ss);
    res[0][r] = l0 - lse; res[1][r] = l1 - lse; res[2][r] = l2 - lse;
  }
#pragma unroll
  for (int t = 0; t < 3; ++t) {
    int c = t * 16 + lr;
    if (c < FOUT) {
#pragma unroll
      for (int r = 0; r < 4; ++r) {
        int node = nbase + g * 4 + r;
        if (node < N) out[(size_t)node * FOUT + c] = res[t][r];
      }
    }
  }
}

// ---------------- host ----------------

static inline size_t align_up(size_t x, size_t a) { return (x + a - 1) & ~(a - 1); }

extern "C" void kernel_launch(void* const* d_in, const int* in_sizes, int n_in,
                              void* d_out, int out_size, void* d_ws, size_t ws_size,
                              hipStream_t stream) {
  const float* x   = (const float*)d_in[0];
  const int*   ei  = (const int*)d_in[1];
  const float* W0  = (const float*)d_in[2];
  const float* b0  = (const float*)d_in[3];
  const float* W1  = (const float*)d_in[4];
  const float* b1  = (const float*)d_in[5];
  const float* W2  = (const float*)d_in[6];
  const float* b2  = (const float*)d_in[7];
  const float* Wfc = (const float*)d_in[8];
  const float* bfc = (const float*)d_in[9];
  float* out = (float*)d_out;

  const int N = in_sizes[0] / FIN;       // 100000
  const int E = in_sizes[1] / 2;         // 1600000
  const int* src = ei;
  const int* dst = ei + E;
  const int KP0 = 512;

  // workspace layout
  char* ws = (char*)d_ws;
  size_t off = 0;
  float* dis = (float*)(ws + off);        off = align_up(off + (size_t)N * 4, 512);
  int* rp = (int*)(ws + off);             off = align_up(off + (size_t)(N + 1) * 4, 512);
  int* bucketCnt = (int*)(ws + off);      off = align_up(off + (NB + 1) * 4, 512);
  int* bucketBase = (int*)(ws + off);     off = align_up(off + (NB + 1) * 4, 512);
  int* bucketFill = (int*)(ws + off);     off = align_up(off + (NB + 1) * 4, 512);
  unsigned* ebin = (unsigned*)(ws + off); off = align_up(off + (size_t)E * 4, 512);
  int2* epackS = (int2*)(ws + off);       off = align_up(off + (size_t)E * 8, 512);
  short* WT0 = (short*)(ws + off);        off = align_up(off + (size_t)128 * KP0 * 2, 512);
  short* WT1 = (short*)(ws + off);        off = align_up(off + (size_t)128 * FH * 2, 512);
  short* WT2 = (short*)(ws + off);        off = align_up(off + (size_t)128 * FH * 2, 512);
  short* WfcT = (short*)(ws + off);       off = align_up(off + (size_t)48 * FH * 2, 512);
  short* hB = (short*)(ws + off);         off = align_up(off + (size_t)N * FH * 2, 512);
  float* scale = (float*)(ws + off);      off = align_up(off + (size_t)N * 4, 512);
  unsigned char* hQ = (unsigned char*)(ws + off); off = align_up(off + (size_t)N * 128, 512);

  const int gN4 = (N + 3) / 4;
  const int gBlk = (E + 2047) / 2048;
  const int NBUSE = (N + 511) / 512;

  // --- bucketed CSR build (scans fused into k_bhist) ---
  hipMemsetAsync(bucketCnt, 0, (NB + 1) * 4, stream);
  hipMemsetAsync(bucketFill, 0, (NB + 1) * 4, stream);
  k_bcount<<<gBlk, 256, 0, stream>>>(dst, bucketCnt, E);
  k_bscan<<<1, NB, 0, stream>>>(bucketCnt, bucketBase);
  k_bin<<<gBlk, 256, 0, stream>>>(src, dst, bucketBase, bucketFill, ebin, E);
  k_bhist<<<NBUSE, 512, 0, stream>>>(ebin, bucketBase, rp, dis, N, E);
  k_fscatter<<<NBUSE, 512, 0, stream>>>(ebin, bucketBase, rp, dis, epackS, N);

  // --- weight prep ---
  k_prep_w<<<(128 * KP0 + 255) / 256, 256, 0, stream>>>(W0, WT0, FIN, KP0);
  k_prep_w<<<(128 * FH + 255) / 256, 256, 0, stream>>>(W1, WT1, FH, FH);
  k_prep_w<<<(128 * FH + 255) / 256, 256, 0, stream>>>(W2, WT2, FH, FH);
  k_prep_wfc<<<(48 * FH + 255) / 256, 256, 0, stream>>>(Wfc, WfcT);

  const int gLog = (N + 63) / 64;

  // --- layer 0: 500 -> 128 ---
  k_gemm_q<512, true><<<256, 512, 0, stream>>>(x, WT0, hQ, scale, N, FIN);
  k_agg<<<gN4, 256, 0, stream>>>((const char*)hQ, scale, (char*)hB, dis, rp, epackS, b0, N);
  // --- layer 1 ---
  k_gemm_q<128, false><<<256, 512, 0, stream>>>(hB, WT1, hQ, scale, N, FH);
  k_agg<<<gN4, 256, 0, stream>>>((const char*)hQ, scale, (char*)hB, dis, rp, epackS, b1, N);
  // --- layer 2 ---
  k_gemm_q<128, false><<<256, 512, 0, stream>>>(hB, WT2, hQ, scale, N, FH);
  k_agg<<<gN4, 256, 0, stream>>>((const char*)hQ, scale, (char*)hB, dis, rp, epackS, b2, N);
  // --- FC + log_softmax ---
  k_logits<<<gLog, 256, 0, stream>>>(hB, WfcT, bfc, out, N);
}